// Round 6
// baseline (634.862 us; speedup 1.0000x reference)
//
#include <hip/hip_runtime.h>
#include <hip/hip_bf16.h>

#define S_LEN  2048
#define BATCH  2
#define DMODEL 1024
#define NHEAD  16
#define DHEAD  64
#define DFF    4096
#define NTOK   (BATCH * S_LEN)
#define QKVLD  3072   // fused Q|K|V output row stride

typedef __attribute__((ext_vector_type(8))) short short8;
typedef __attribute__((ext_vector_type(4))) short short4v;
typedef __attribute__((ext_vector_type(4))) float f32x4;

__device__ __forceinline__ short f2bs(float f) {
  __hip_bfloat16 h = __float2bfloat16(f);
  short s;
  __builtin_memcpy(&s, &h, sizeof(short));
  return s;
}

__device__ __forceinline__ float bs2f(short s) {
  unsigned u = ((unsigned)(unsigned short)s) << 16;
  float f;
  __builtin_memcpy(&f, &u, sizeof(float));
  return f;
}

__device__ __forceinline__ f32x4 mfma16(short8 a, short8 b, f32x4 c) {
  return __builtin_amdgcn_mfma_f32_16x16x32_bf16(a, b, c, 0, 0, 0);
}

// async global->LDS, 16B per lane; LDS dest = wave-uniform base + lane*16
__device__ __forceinline__ void load_lds16(const short* g, short* l) {
  __builtin_amdgcn_global_load_lds(
      (const __attribute__((address_space(1))) void*)g,
      (__attribute__((address_space(3))) void*)l, 16, 0, 0);
}

// ---------------------------------------------------------------------------
// Weight transpose + cast + scale: in f32 [R][C] -> out bf16 [C][R] * scale
// ---------------------------------------------------------------------------
__global__ void transpose_cast(const float* __restrict__ in, short* __restrict__ out,
                               int R, int C, float scale) {
  __shared__ float tile[32][33];
  const int c0 = blockIdx.x * 32, r0 = blockIdx.y * 32;
  const int tx = threadIdx.x, ty = threadIdx.y;  // 32 x 8
#pragma unroll
  for (int i = 0; i < 32; i += 8)
    tile[ty + i][tx] = in[(size_t)(r0 + ty + i) * C + c0 + tx];
  __syncthreads();
#pragma unroll
  for (int i = 0; i < 32; i += 8)
    out[(size_t)(c0 + ty + i) * R + r0 + tx] = f2bs(tile[tx][ty + i] * scale);
}

// ---------------------------------------------------------------------------
// bf16 transpose: in [R][LDin] -> out [C][R], 64x64 tiles
// ---------------------------------------------------------------------------
__global__ __launch_bounds__(256) void transpose_bf16(
    const short* __restrict__ in, short* __restrict__ out, int R, int LDin) {
  __shared__ __attribute__((aligned(16))) short tile[64][72];
  const int c0 = blockIdx.x * 64, r0 = blockIdx.y * 64;
#pragma unroll
  for (int i = 0; i < 2; i++) {
    const int idx = threadIdx.x + 256 * i;
    const int rr = idx >> 3, cc8 = (idx & 7) * 8;
    *(int4*)(&tile[rr][cc8]) = *(const int4*)(in + (size_t)(r0 + rr) * LDin + c0 + cc8);
  }
  __syncthreads();
#pragma unroll
  for (int i = 0; i < 2; i++) {
    const int idx = threadIdx.x + 256 * i;
    const int rr = idx >> 3, cc8 = (idx & 7) * 8;
    short8 v;
#pragma unroll
    for (int j = 0; j < 8; j++) v[j] = tile[cc8 + j][rr];
    *(short8*)(out + (size_t)(c0 + rr) * R + r0 + cc8) = v;
  }
}

// ---------------------------------------------------------------------------
// bqkv: [0,1024)=bq*0.125, [1024,2048)=bk, [2048,3072)=bv
// ---------------------------------------------------------------------------
__global__ void concat_bias(const float* __restrict__ bq, const float* __restrict__ bk,
                            const float* __restrict__ bv, float* __restrict__ bqkv) {
  const int i = blockIdx.x * 256 + threadIdx.x;
  float v;
  if (i < DMODEL) v = bq[i] * 0.125f;
  else if (i < 2 * DMODEL) v = bk[i - DMODEL];
  else v = bv[i - 2 * DMODEL];
  bqkv[i] = v;
}

// ---------------------------------------------------------------------------
// Token prep: qkb = bf16(src+pos), srcb = bf16(src)
// ---------------------------------------------------------------------------
__global__ void prep_tokens(const float* __restrict__ src, const float* __restrict__ pos,
                            short* __restrict__ qkb, short* __restrict__ srcb) {
  const int i = (blockIdx.x * blockDim.x + threadIdx.x) * 4;
  float4 s = *(const float4*)(src + i);
  float4 p = *(const float4*)(pos + i);
  short4v q4 = {f2bs(s.x + p.x), f2bs(s.y + p.y), f2bs(s.z + p.z), f2bs(s.w + p.w)};
  short4v s4 = {f2bs(s.x), f2bs(s.y), f2bs(s.z), f2bs(s.w)};
  *(short4v*)(qkb + i) = q4;
  *(short4v*)(srcb + i) = s4;
}

// ---------------------------------------------------------------------------
// corr f32 -> bf16
// ---------------------------------------------------------------------------
__global__ void prep_corr(const float* __restrict__ corr, short* __restrict__ corrb) {
  const size_t i = ((size_t)blockIdx.x * 256 + threadIdx.x) * 4;
  float4 c = *(const float4*)(corr + i);
  short4v o = {f2bs(c.x), f2bs(c.y), f2bs(c.z), f2bs(c.w)};
  *(short4v*)(corrb + i) = o;
}

// ---------------------------------------------------------------------------
// out[token][d] = bias[d] broadcast (pre-init for atomic split-K GEMMs)
// ---------------------------------------------------------------------------
__global__ void init_bias(const float* __restrict__ bias, float* __restrict__ out) {
  const size_t i = ((size_t)blockIdx.x * 256 + threadIdx.x) * 4;
  *(f32x4*)(out + i) = *(const f32x4*)(bias + (i & (DMODEL - 1)));
}

// ---------------------------------------------------------------------------
// GEMM 128x128 (m97-style), dual-A: column blocks with col0 < splitcol read
// A0, others A1 (for fused QKV: Q/K from src+pos, V from src).
// ---------------------------------------------------------------------------
template <int RELU, int OUT_BF16>
__global__ __launch_bounds__(256) void gemm_bt(
    const short* __restrict__ A0, const short* __restrict__ A1,
    const short* __restrict__ Bt, const float* __restrict__ bias,
    float* __restrict__ Cf, short* __restrict__ Cb,
    int M, int N, int K, int splitcol) {
  __shared__ __attribute__((aligned(16))) short As[128 * 32];
  __shared__ __attribute__((aligned(16))) short Bs[128 * 32];

  const int tid = threadIdx.x;
  const int wave = tid >> 6, lane = tid & 63;
  const int lm = lane & 15, lq = lane >> 4;
  const int row0 = blockIdx.y * 128, col0 = blockIdx.x * 128;
  const int wr = (wave >> 1) * 64, wc = (wave & 1) * 64;

  const short* A = (col0 < splitcol) ? A0 : A1;
  const short* ag = A + (size_t)(row0 + wave * 32 + (lane >> 2)) * K + (lane & 3) * 8;
  const short* bg = Bt + (size_t)(col0 + wave * 32 + (lane >> 2)) * K + (lane & 3) * 8;
  short* asl = &As[wave * 32 * 32];
  short* bsl = &Bs[wave * 32 * 32];

  f32x4 acc[4][4];
#pragma unroll
  for (int i = 0; i < 4; i++)
#pragma unroll
    for (int j = 0; j < 4; j++) acc[i][j] = (f32x4){0.f, 0.f, 0.f, 0.f};

  for (int k0 = 0; k0 < K; k0 += 32) {
    load_lds16(ag + k0, asl);
    load_lds16(ag + (size_t)16 * K + k0, asl + 16 * 32);
    load_lds16(bg + k0, bsl);
    load_lds16(bg + (size_t)16 * K + k0, bsl + 16 * 32);
    __syncthreads();

    short8 af[4], bfr[4];
#pragma unroll
    for (int i = 0; i < 4; i++)
      af[i] = *(const short8*)(&As[(wr + 16 * i + lm) * 32 + lq * 8]);
#pragma unroll
    for (int j = 0; j < 4; j++)
      bfr[j] = *(const short8*)(&Bs[(wc + 16 * j + lm) * 32 + lq * 8]);
#pragma unroll
    for (int i = 0; i < 4; i++)
#pragma unroll
      for (int j = 0; j < 4; j++) acc[i][j] = mfma16(af[i], bfr[j], acc[i][j]);
    __syncthreads();
  }

#pragma unroll
  for (int i = 0; i < 4; i++) {
#pragma unroll
    for (int j = 0; j < 4; j++) {
      const int col = col0 + wc + 16 * j + lm;
      const float bs = bias[col];
#pragma unroll
      for (int r = 0; r < 4; r++) {
        const int row = row0 + wr + 16 * i + lq * 4 + r;
        float v = acc[i][j][r] + bs;
        if (RELU) v = fmaxf(v, 0.f);
        if (OUT_BF16)
          Cb[(size_t)row * N + col] = f2bs(v);
        else
          Cf[(size_t)row * N + col] = v;
      }
    }
  }
}

// ---------------------------------------------------------------------------
// Split-K GEMM 128x128: accumulates into pre-biased f32 C via atomic f32 add.
// Grid z = K-split index, each block does Kslice of the reduction.
// ---------------------------------------------------------------------------
__global__ __launch_bounds__(256) void gemm_bt_splitk(
    const short* __restrict__ A, const short* __restrict__ Bt,
    float* __restrict__ Cf, int M, int N, int K, int Kslice) {
  __shared__ __attribute__((aligned(16))) short As[128 * 32];
  __shared__ __attribute__((aligned(16))) short Bs[128 * 32];

  const int tid = threadIdx.x;
  const int wave = tid >> 6, lane = tid & 63;
  const int lm = lane & 15, lq = lane >> 4;
  const int row0 = blockIdx.y * 128, col0 = blockIdx.x * 128;
  const int kbase = blockIdx.z * Kslice;
  const int wr = (wave >> 1) * 64, wc = (wave & 1) * 64;

  const short* ag = A + (size_t)(row0 + wave * 32 + (lane >> 2)) * K + (lane & 3) * 8;
  const short* bg = Bt + (size_t)(col0 + wave * 32 + (lane >> 2)) * K + (lane & 3) * 8;
  short* asl = &As[wave * 32 * 32];
  short* bsl = &Bs[wave * 32 * 32];

  f32x4 acc[4][4];
#pragma unroll
  for (int i = 0; i < 4; i++)
#pragma unroll
    for (int j = 0; j < 4; j++) acc[i][j] = (f32x4){0.f, 0.f, 0.f, 0.f};

  for (int k0 = kbase; k0 < kbase + Kslice; k0 += 32) {
    load_lds16(ag + k0, asl);
    load_lds16(ag + (size_t)16 * K + k0, asl + 16 * 32);
    load_lds16(bg + k0, bsl);
    load_lds16(bg + (size_t)16 * K + k0, bsl + 16 * 32);
    __syncthreads();

    short8 af[4], bfr[4];
#pragma unroll
    for (int i = 0; i < 4; i++)
      af[i] = *(const short8*)(&As[(wr + 16 * i + lm) * 32 + lq * 8]);
#pragma unroll
    for (int j = 0; j < 4; j++)
      bfr[j] = *(const short8*)(&Bs[(wc + 16 * j + lm) * 32 + lq * 8]);
#pragma unroll
    for (int i = 0; i < 4; i++)
#pragma unroll
      for (int j = 0; j < 4; j++) acc[i][j] = mfma16(af[i], bfr[j], acc[i][j]);
    __syncthreads();
  }

#pragma unroll
  for (int i = 0; i < 4; i++) {
#pragma unroll
    for (int j = 0; j < 4; j++) {
      const int col = col0 + wc + 16 * j + lm;
#pragma unroll
      for (int r = 0; r < 4; r++) {
        const int row = row0 + wr + 16 * i + lq * 4 + r;
        unsafeAtomicAdd(&Cf[(size_t)row * N + col], acc[i][j][r]);
      }
    }
  }
}

// ---------------------------------------------------------------------------
// Fused attention, S^T form, non-online softmax, split-K x2, BARRIER-FREE.
// K/V fragments loaded directly from global (8 KB tiles live in L1, shared
// by the block's 4 waves). Only per-wave P roundtrip uses LDS. corr in bf16.
// Grid (NHEAD, S_LEN/128, BATCH*2); 4 waves x 32 queries.
// ---------------------------------------------------------------------------
__global__ __launch_bounds__(256, 4) void attn_kernel(
    const short* __restrict__ QKV,   // [NTOK][3072]: Q*0.125 | K | V
    const short* __restrict__ VT,    // [DMODEL][NTOK]
    const short* __restrict__ corrb, // [B][S][S] bf16
    float* __restrict__ Op,          // [2][NTOK][DMODEL] partial numerators
    float* __restrict__ lp) {        // [2][NTOK][NHEAD] partial denominators
  const int h = blockIdx.x, qtile = blockIdx.y;
  const int b = blockIdx.z >> 1, split = blockIdx.z & 1;
  const int koff = split * (S_LEN / 2);
  const int tid = threadIdx.x;
  const int wave = tid >> 6, lane = tid & 63;
  const int lm = lane & 15, lq = lane >> 4;
  const int qb = qtile * 128 + wave * 32;

  __shared__ __attribute__((aligned(16))) short Ps[4][32][72];  // per-wave [q][key]

  const short* q0 = QKV + (size_t)(b * S_LEN + qb + lm) * QKVLD + h * DHEAD;
  const short* q1 = q0 + (size_t)16 * QKVLD;
  const short8 qA0 = *(const short8*)(q0 + lq * 8);
  const short8 qA1 = *(const short8*)(q0 + lq * 8 + 32);
  const short8 qB0 = *(const short8*)(q1 + lq * 8);
  const short8 qB1 = *(const short8*)(q1 + lq * 8 + 32);

  f32x4 oA[4], oB[4];
#pragma unroll
  for (int t = 0; t < 4; t++) {
    oA[t] = (f32x4){0.f, 0.f, 0.f, 0.f};
    oB[t] = (f32x4){0.f, 0.f, 0.f, 0.f};
  }
  f32x4 laccA = (f32x4){0.f, 0.f, 0.f, 0.f};
  f32x4 laccB = (f32x4){0.f, 0.f, 0.f, 0.f};

  // K fragment base: row = key, dims of head h. V^T base: row = dim, col = key.
  const short* Kbase = QKV + (size_t)(b * S_LEN) * QKVLD + DMODEL + h * DHEAD + lq * 8;
  const short* Vbase = VT + (size_t)(h * DHEAD + lm) * NTOK + b * S_LEN + lq * 8;
  const short* c0 = corrb + (size_t)(b * S_LEN + qb + lm) * S_LEN;
  const short* c1 = c0 + (size_t)16 * S_LEN;

  for (int kt = koff; kt < koff + S_LEN / 2; kt += 64) {
    // --- corr loads for this tile (bf16, 8B each)
    short4v crA[4], crB[4];
#pragma unroll
    for (int t = 0; t < 4; t++) {
      crA[t] = *(const short4v*)(c0 + kt + t * 16 + lq * 4);
      crB[t] = *(const short4v*)(c1 + kt + t * 16 + lq * 4);
    }

    // --- scores S^T: K frags straight from global (L1-resident)
    f32x4 svA[4], svB[4];
#pragma unroll
    for (int t = 0; t < 4; t++) {
      const short* kp = Kbase + (size_t)(kt + t * 16 + lm) * QKVLD;
      const short8 kf0 = *(const short8*)kp;
      const short8 kf1 = *(const short8*)(kp + 32);
      f32x4 a = (f32x4){0.f, 0.f, 0.f, 0.f};
      a = mfma16(kf0, qA0, a);
      a = mfma16(kf1, qA1, a);
      svA[t] = a;
      f32x4 c = (f32x4){0.f, 0.f, 0.f, 0.f};
      c = mfma16(kf0, qB0, c);
      c = mfma16(kf1, qB1, c);
      svB[t] = c;
    }

    // --- exp(s + corr), accumulate row sums, pack P into per-wave LDS
#pragma unroll
    for (int t = 0; t < 4; t++) {
#pragma unroll
      for (int r = 0; r < 4; r++) {
        svA[t][r] = __expf(svA[t][r] + bs2f(crA[t][r]));
        svB[t][r] = __expf(svB[t][r] + bs2f(crB[t][r]));
      }
      laccA += svA[t];
      laccB += svB[t];
      short4v pA = {f2bs(svA[t][0]), f2bs(svA[t][1]), f2bs(svA[t][2]), f2bs(svA[t][3])};
      short4v pB = {f2bs(svB[t][0]), f2bs(svB[t][1]), f2bs(svB[t][2]), f2bs(svB[t][3])};
      *(short4v*)(&Ps[wave][lm][t * 16 + lq * 4]) = pA;
      *(short4v*)(&Ps[wave][16 + lm][t * 16 + lq * 4]) = pB;
    }

    // --- PV: V frags straight from global (L1-resident), P from LDS
    const short8 pA0 = *(const short8*)(&Ps[wave][lm][lq * 8]);
    const short8 pA1 = *(const short8*)(&Ps[wave][lm][32 + lq * 8]);
    const short8 pB0 = *(const short8*)(&Ps[wave][16 + lm][lq * 8]);
    const short8 pB1 = *(const short8*)(&Ps[wave][16 + lm][32 + lq * 8]);
#pragma unroll
    for (int t = 0; t < 4; t++) {
      const short* vp = Vbase + (size_t)(t * 16) * NTOK + kt;
      const short8 vf0 = *(const short8*)vp;
      const short8 vf1 = *(const short8*)(vp + 32);
      oA[t] = mfma16(vf0, pA0, oA[t]);
      oA[t] = mfma16(vf1, pA1, oA[t]);
      oB[t] = mfma16(vf0, pB0, oB[t]);
      oB[t] = mfma16(vf1, pB1, oB[t]);
    }
  }

  // --- epilogue: partial sums out (no divide)
  float lA = laccA[0] + laccA[1] + laccA[2] + laccA[3];
  float lB = laccB[0] + laccB[1] + laccB[2] + laccB[3];
  lA += __shfl_xor(lA, 16);
  lA += __shfl_xor(lA, 32);
  lB += __shfl_xor(lB, 16);
  lB += __shfl_xor(lB, 32);
  if (lq == 0) {
    lp[((size_t)split * NTOK + b * S_LEN + qb + lm) * NHEAD + h] = lA;
    lp[((size_t)split * NTOK + b * S_LEN + qb + 16 + lm) * NHEAD + h] = lB;
  }
  float* opA = Op + (size_t)split * NTOK * DMODEL +
               (size_t)(b * S_LEN + qb + lm) * DMODEL + h * DHEAD;
  float* opB = opA + (size_t)16 * DMODEL;
#pragma unroll
  for (int t = 0; t < 4; t++) {
    *(f32x4*)(opA + t * 16 + lq * 4) = oA[t];
    *(f32x4*)(opB + t * 16 + lq * 4) = oB[t];
  }
}

// ---------------------------------------------------------------------------
// Combine split-K partials: ctx = (O0+O1)/(l0+l1), bf16
// ---------------------------------------------------------------------------
__global__ __launch_bounds__(256) void combine_ctx(
    const float* __restrict__ Op, const float* __restrict__ lp,
    short* __restrict__ ctx) {
  const size_t idx = ((size_t)blockIdx.x * 256 + threadIdx.x) * 4;
  const int token = (int)(idx >> 10);
  const int d = (int)(idx & 1023);
  const int h = d >> 6;
  const f32x4 o0 = *(const f32x4*)(Op + idx);
  const f32x4 o1 = *(const f32x4*)(Op + (size_t)NTOK * DMODEL + idx);
  const float l0 = lp[(size_t)token * NHEAD + h];
  const float l1 = lp[((size_t)NTOK + token) * NHEAD + h];
  const float inv = 1.0f / (l0 + l1);
  short4v ov = {f2bs((o0[0] + o1[0]) * inv), f2bs((o0[1] + o1[1]) * inv),
                f2bs((o0[2] + o1[2]) * inv), f2bs((o0[3] + o1[3]) * inv)};
  *(short4v*)(ctx + idx) = ov;
}

// ---------------------------------------------------------------------------
// Residual + LayerNorm over 1024 dims. One block (256 thr) per token row.
// ---------------------------------------------------------------------------
__global__ __launch_bounds__(256) void residual_ln(
    const float* __restrict__ xa, const float* __restrict__ xb,
    const float* __restrict__ g, const float* __restrict__ be,
    float* __restrict__ outf, short* __restrict__ outb) {
  const int row = blockIdx.x;
  const int t = threadIdx.x;
  const size_t base = (size_t)row * DMODEL + t * 4;
  float4 a = *(const float4*)(xa + base);
  float4 b = *(const float4*)(xb + base);
  const float v0 = a.x + b.x, v1 = a.y + b.y, v2 = a.z + b.z, v3 = a.w + b.w;
  float sum = v0 + v1 + v2 + v3;
  float sq = v0 * v0 + v1 * v1 + v2 * v2 + v3 * v3;
#pragma unroll
  for (int off = 1; off < 64; off <<= 1) {
    sum += __shfl_xor(sum, off);
    sq += __shfl_xor(sq, off);
  }
  __shared__ float ssum[4], ssq[4];
  const int wave = t >> 6;
  if ((t & 63) == 0) { ssum[wave] = sum; ssq[wave] = sq; }
  __syncthreads();
  sum = ssum[0] + ssum[1] + ssum[2] + ssum[3];
  sq = ssq[0] + ssq[1] + ssq[2] + ssq[3];
  const float mean = sum * (1.0f / DMODEL);
  const float var = sq * (1.0f / DMODEL) - mean * mean;
  const float rstd = rsqrtf(var + 1e-5f);
  float4 gv = *(const float4*)(g + t * 4);
  float4 bv = *(const float4*)(be + t * 4);
  const float o0 = (v0 - mean) * rstd * gv.x + bv.x;
  const float o1 = (v1 - mean) * rstd * gv.y + bv.y;
  const float o2 = (v2 - mean) * rstd * gv.z + bv.z;
  const float o3 = (v3 - mean) * rstd * gv.w + bv.w;
  if (outf) {
    float4 ov = {o0, o1, o2, o3};
    *(float4*)(outf + base) = ov;
  }
  if (outb) {
    short4v ob = {f2bs(o0), f2bs(o1), f2bs(o2), f2bs(o3)};
    *(short4v*)(outb + base) = ob;
  }
}

// ---------------------------------------------------------------------------
extern "C" void kernel_launch(void* const* d_in, const int* in_sizes, int n_in,
                              void* d_out, int out_size, void* d_ws, size_t ws_size,
                              hipStream_t stream) {
  const float* src = (const float*)d_in[0];
  const float* corr = (const float*)d_in[1];
  const float* pos = (const float*)d_in[2];
  const float* Wq = (const float*)d_in[3];
  const float* bq = (const float*)d_in[4];
  const float* Wk = (const float*)d_in[5];
  const float* bk = (const float*)d_in[6];
  const float* Wv = (const float*)d_in[7];
  const float* bv = (const float*)d_in[8];
  const float* Wo = (const float*)d_in[9];
  const float* bo = (const float*)d_in[10];
  const float* W1 = (const float*)d_in[11];
  const float* b1 = (const float*)d_in[12];
  const float* W2 = (const float*)d_in[13];
  const float* b2 = (const float*)d_in[14];
  const float* g1 = (const float*)d_in[15];
  const float* be1 = (const float*)d_in[16];
  const float* g2 = (const float*)d_in[17];
  const float* be2 = (const float*)d_in[18];
  float* out = (float*)d_out;

  char* ws = (char*)d_ws;
  size_t off = 0;
  auto alloc = [&](size_t bytes) {
    char* p = ws + off;
    off += (bytes + 255) & ~(size_t)255;
    return p;
  };
  short* WqkvT = (short*)alloc((size_t)QKVLD * DMODEL * 2);  // [3072][1024]
  short* WoT = (short*)alloc((size_t)DMODEL * DMODEL * 2);
  short* W1T = (short*)alloc((size_t)DFF * DMODEL * 2);
  short* W2T = (short*)alloc((size_t)DMODEL * DFF * 2);
  float* bqkv = (float*)alloc((size_t)QKVLD * 4);
  short* qkb = (short*)alloc((size_t)NTOK * DMODEL * 2);
  short* srcb = (short*)alloc((size_t)NTOK * DMODEL * 2);
  short* QKVb = (short*)alloc((size_t)NTOK * QKVLD * 2);   // fused Q|K|V (24 MB)
  short* VTt = (short*)alloc((size_t)DMODEL * NTOK * 2);
  short* corrb = (short*)alloc((size_t)BATCH * S_LEN * S_LEN * 2);  // 16.8 MB
  short* ctxb = (short*)alloc((size_t)NTOK * DMODEL * 2);
  float* lp = (float*)alloc((size_t)2 * NTOK * NHEAD * 4);
  float* attn_out = (float*)alloc((size_t)NTOK * DMODEL * 4);  // also Yf (disjoint)
  float* x1f = (float*)alloc((size_t)NTOK * DMODEL * 4);
  short* x1b = (short*)alloc((size_t)NTOK * DMODEL * 2);
  short* Hb = (short*)alloc((size_t)NTOK * DFF * 2);       // 33.6 MB, also Op (disjoint)
  float* Op = (float*)Hb;                                  // [2][NTOK][DMODEL] f32
  float* Yf = attn_out;

  const dim3 tb(32, 8);
  transpose_cast<<<dim3(32, 32), tb, 0, stream>>>(Wq, WqkvT, DMODEL, DMODEL, 0.125f);
  transpose_cast<<<dim3(32, 32), tb, 0, stream>>>(Wk, WqkvT + (size_t)DMODEL * DMODEL,
                                                  DMODEL, DMODEL, 1.0f);
  transpose_cast<<<dim3(32, 32), tb, 0, stream>>>(Wv, WqkvT + (size_t)2 * DMODEL * DMODEL,
                                                  DMODEL, DMODEL, 1.0f);
  transpose_cast<<<dim3(32, 32), tb, 0, stream>>>(Wo, WoT, DMODEL, DMODEL, 1.0f);
  transpose_cast<<<dim3(128, 32), tb, 0, stream>>>(W1, W1T, DMODEL, DFF, 1.0f);
  transpose_cast<<<dim3(32, 128), tb, 0, stream>>>(W2, W2T, DFF, DMODEL, 1.0f);
  concat_bias<<<QKVLD / 256, 256, 0, stream>>>(bq, bk, bv, bqkv);

  prep_tokens<<<(NTOK * DMODEL) / (256 * 4), 256, 0, stream>>>(src, pos, qkb, srcb);
  prep_corr<<<(BATCH * S_LEN * S_LEN) / (256 * 4), 256, 0, stream>>>(corr, corrb);

  // fused Q|K|V projection: cols<2048 use qkb, cols>=2048 use srcb
  gemm_bt<0, 1><<<dim3(QKVLD / 128, NTOK / 128), 256, 0, stream>>>(
      qkb, srcb, WqkvT, bqkv, nullptr, QKVb, NTOK, QKVLD, DMODEL, 2048);

  // V^T for attention PV a-operand (V = cols 2048.. of QKVb)
  transpose_bf16<<<dim3(DMODEL / 64, NTOK / 64), 256, 0, stream>>>(
      QKVb + 2048, VTt, NTOK, QKVLD);

  // attention, split-K x2, barrier-free (1024 blocks)
  attn_kernel<<<dim3(NHEAD, S_LEN / 128, BATCH * 2), 256, 0, stream>>>(
      QKVb, VTt, corrb, Op, lp);
  combine_ctx<<<(NTOK * DMODEL) / (256 * 4), 256, 0, stream>>>(Op, lp, ctxb);

  // output projection: split-K x2 atomic into bias-initialized attn_out
  init_bias<<<(NTOK * DMODEL) / (256 * 4), 256, 0, stream>>>(bo, attn_out);
  gemm_bt_splitk<<<dim3(DMODEL / 128, NTOK / 128, 2), 256, 0, stream>>>(
      ctxb, WoT, attn_out, NTOK, DMODEL, DMODEL, DMODEL / 2);

  // LN1
  residual_ln<<<NTOK, 256, 0, stream>>>(src, attn_out, g1, be1, x1f, x1b);

  // FFN1 (128x128, 1024 blocks)
  gemm_bt<1, 1><<<dim3(DFF / 128, NTOK / 128), 256, 0, stream>>>(
      x1b, x1b, W1T, b1, nullptr, Hb, NTOK, DFF, DMODEL, 1 << 30);

  // FFN2: split-K x4 atomic into bias-initialized Yf (1024 blocks)
  init_bias<<<(NTOK * DMODEL) / (256 * 4), 256, 0, stream>>>(b2, Yf);
  gemm_bt_splitk<<<dim3(DMODEL / 128, NTOK / 128, 4), 256, 0, stream>>>(
      Hb, W2T, Yf, NTOK, DMODEL, DFF, DFF / 4);

  // LN2 -> output
  residual_ln<<<NTOK, 256, 0, stream>>>(x1f, Yf, g2, be2, out, nullptr);
}

// Round 7
// 486.615 us; speedup vs baseline: 1.3046x; 1.3046x over previous
//
#include <hip/hip_runtime.h>
#include <hip/hip_bf16.h>

#define S_LEN  2048
#define BATCH  2
#define DMODEL 1024
#define NHEAD  16
#define DHEAD  64
#define DFF    4096
#define NTOK   (BATCH * S_LEN)
#define QKVLD  3072   // fused Q|K|V output row stride

typedef __attribute__((ext_vector_type(8))) short short8;
typedef __attribute__((ext_vector_type(4))) short short4v;
typedef __attribute__((ext_vector_type(4))) float f32x4;

__device__ __forceinline__ short f2bs(float f) {
  __hip_bfloat16 h = __float2bfloat16(f);
  short s;
  __builtin_memcpy(&s, &h, sizeof(short));
  return s;
}

__device__ __forceinline__ float bs2f(short s) {
  unsigned u = ((unsigned)(unsigned short)s) << 16;
  float f;
  __builtin_memcpy(&f, &u, sizeof(float));
  return f;
}

__device__ __forceinline__ f32x4 mfma16(short8 a, short8 b, f32x4 c) {
  return __builtin_amdgcn_mfma_f32_16x16x32_bf16(a, b, c, 0, 0, 0);
}

// async global->LDS, 16B per lane; LDS dest = wave-uniform base + lane*16
__device__ __forceinline__ void load_lds16(const short* g, short* l) {
  __builtin_amdgcn_global_load_lds(
      (const __attribute__((address_space(1))) void*)g,
      (__attribute__((address_space(3))) void*)l, 16, 0, 0);
}

// ---------------------------------------------------------------------------
// Weight transpose + cast + scale: in f32 [R][C] -> out bf16 [C][R] * scale
// ---------------------------------------------------------------------------
__global__ void transpose_cast(const float* __restrict__ in, short* __restrict__ out,
                               int R, int C, float scale) {
  __shared__ float tile[32][33];
  const int c0 = blockIdx.x * 32, r0 = blockIdx.y * 32;
  const int tx = threadIdx.x, ty = threadIdx.y;  // 32 x 8
#pragma unroll
  for (int i = 0; i < 32; i += 8)
    tile[ty + i][tx] = in[(size_t)(r0 + ty + i) * C + c0 + tx];
  __syncthreads();
#pragma unroll
  for (int i = 0; i < 32; i += 8)
    out[(size_t)(c0 + ty + i) * R + r0 + tx] = f2bs(tile[tx][ty + i] * scale);
}

// ---------------------------------------------------------------------------
// bf16 transpose: in [R][LDin] -> out [C][R], 64x64 tiles
// ---------------------------------------------------------------------------
__global__ __launch_bounds__(256) void transpose_bf16(
    const short* __restrict__ in, short* __restrict__ out, int R, int LDin) {
  __shared__ __attribute__((aligned(16))) short tile[64][72];
  const int c0 = blockIdx.x * 64, r0 = blockIdx.y * 64;
#pragma unroll
  for (int i = 0; i < 2; i++) {
    const int idx = threadIdx.x + 256 * i;
    const int rr = idx >> 3, cc8 = (idx & 7) * 8;
    *(int4*)(&tile[rr][cc8]) = *(const int4*)(in + (size_t)(r0 + rr) * LDin + c0 + cc8);
  }
  __syncthreads();
#pragma unroll
  for (int i = 0; i < 2; i++) {
    const int idx = threadIdx.x + 256 * i;
    const int rr = idx >> 3, cc8 = (idx & 7) * 8;
    short8 v;
#pragma unroll
    for (int j = 0; j < 8; j++) v[j] = tile[cc8 + j][rr];
    *(short8*)(out + (size_t)(c0 + rr) * R + r0 + cc8) = v;
  }
}

// ---------------------------------------------------------------------------
// bqkv: [0,1024)=bq*0.125, [1024,2048)=bk, [2048,3072)=bv
// ---------------------------------------------------------------------------
__global__ void concat_bias(const float* __restrict__ bq, const float* __restrict__ bk,
                            const float* __restrict__ bv, float* __restrict__ bqkv) {
  const int i = blockIdx.x * 256 + threadIdx.x;
  float v;
  if (i < DMODEL) v = bq[i] * 0.125f;
  else if (i < 2 * DMODEL) v = bk[i - DMODEL];
  else v = bv[i - 2 * DMODEL];
  bqkv[i] = v;
}

// ---------------------------------------------------------------------------
// Token prep: qkb = bf16(src+pos), srcb = bf16(src)
// ---------------------------------------------------------------------------
__global__ void prep_tokens(const float* __restrict__ src, const float* __restrict__ pos,
                            short* __restrict__ qkb, short* __restrict__ srcb) {
  const int i = (blockIdx.x * blockDim.x + threadIdx.x) * 4;
  float4 s = *(const float4*)(src + i);
  float4 p = *(const float4*)(pos + i);
  short4v q4 = {f2bs(s.x + p.x), f2bs(s.y + p.y), f2bs(s.z + p.z), f2bs(s.w + p.w)};
  short4v s4 = {f2bs(s.x), f2bs(s.y), f2bs(s.z), f2bs(s.w)};
  *(short4v*)(qkb + i) = q4;
  *(short4v*)(srcb + i) = s4;
}

// ---------------------------------------------------------------------------
// corr f32 -> bf16
// ---------------------------------------------------------------------------
__global__ void prep_corr(const float* __restrict__ corr, short* __restrict__ corrb) {
  const size_t i = ((size_t)blockIdx.x * 256 + threadIdx.x) * 4;
  float4 c = *(const float4*)(corr + i);
  short4v o = {f2bs(c.x), f2bs(c.y), f2bs(c.z), f2bs(c.w)};
  *(short4v*)(corrb + i) = o;
}

// ---------------------------------------------------------------------------
// GEMM 128x128 (m97-style), dual-A: column blocks with col0 < splitcol read
// A0, others A1 (for fused QKV: Q/K from src+pos, V from src).
// ---------------------------------------------------------------------------
template <int RELU, int OUT_BF16>
__global__ __launch_bounds__(256) void gemm_bt(
    const short* __restrict__ A0, const short* __restrict__ A1,
    const short* __restrict__ Bt, const float* __restrict__ bias,
    float* __restrict__ Cf, short* __restrict__ Cb,
    int M, int N, int K, int splitcol) {
  __shared__ __attribute__((aligned(16))) short As[128 * 32];
  __shared__ __attribute__((aligned(16))) short Bs[128 * 32];

  const int tid = threadIdx.x;
  const int wave = tid >> 6, lane = tid & 63;
  const int lm = lane & 15, lq = lane >> 4;
  const int row0 = blockIdx.y * 128, col0 = blockIdx.x * 128;
  const int wr = (wave >> 1) * 64, wc = (wave & 1) * 64;

  const short* A = (col0 < splitcol) ? A0 : A1;
  const short* ag = A + (size_t)(row0 + wave * 32 + (lane >> 2)) * K + (lane & 3) * 8;
  const short* bg = Bt + (size_t)(col0 + wave * 32 + (lane >> 2)) * K + (lane & 3) * 8;
  short* asl = &As[wave * 32 * 32];
  short* bsl = &Bs[wave * 32 * 32];

  f32x4 acc[4][4];
#pragma unroll
  for (int i = 0; i < 4; i++)
#pragma unroll
    for (int j = 0; j < 4; j++) acc[i][j] = (f32x4){0.f, 0.f, 0.f, 0.f};

  for (int k0 = 0; k0 < K; k0 += 32) {
    load_lds16(ag + k0, asl);
    load_lds16(ag + (size_t)16 * K + k0, asl + 16 * 32);
    load_lds16(bg + k0, bsl);
    load_lds16(bg + (size_t)16 * K + k0, bsl + 16 * 32);
    __syncthreads();

    short8 af[4], bfr[4];
#pragma unroll
    for (int i = 0; i < 4; i++)
      af[i] = *(const short8*)(&As[(wr + 16 * i + lm) * 32 + lq * 8]);
#pragma unroll
    for (int j = 0; j < 4; j++)
      bfr[j] = *(const short8*)(&Bs[(wc + 16 * j + lm) * 32 + lq * 8]);
#pragma unroll
    for (int i = 0; i < 4; i++)
#pragma unroll
      for (int j = 0; j < 4; j++) acc[i][j] = mfma16(af[i], bfr[j], acc[i][j]);
    __syncthreads();
  }

#pragma unroll
  for (int i = 0; i < 4; i++) {
#pragma unroll
    for (int j = 0; j < 4; j++) {
      const int col = col0 + wc + 16 * j + lm;
      const float bs = bias[col];
#pragma unroll
      for (int r = 0; r < 4; r++) {
        const int row = row0 + wr + 16 * i + lq * 4 + r;
        float v = acc[i][j][r] + bs;
        if (RELU) v = fmaxf(v, 0.f);
        if (OUT_BF16)
          Cb[(size_t)row * N + col] = f2bs(v);
        else
          Cf[(size_t)row * N + col] = v;
      }
    }
  }
}

// ---------------------------------------------------------------------------
// Split-K GEMM 128x128: block z covers K range [z*Kslice, (z+1)*Kslice),
// writes f32 partial (no bias) to Cf + z*M*N. No atomics.
// ---------------------------------------------------------------------------
__global__ __launch_bounds__(256) void gemm_bt_part(
    const short* __restrict__ A, const short* __restrict__ Bt,
    float* __restrict__ Cf, int M, int N, int K, int Kslice) {
  __shared__ __attribute__((aligned(16))) short As[128 * 32];
  __shared__ __attribute__((aligned(16))) short Bs[128 * 32];

  const int tid = threadIdx.x;
  const int wave = tid >> 6, lane = tid & 63;
  const int lm = lane & 15, lq = lane >> 4;
  const int row0 = blockIdx.y * 128, col0 = blockIdx.x * 128;
  const int kbase = blockIdx.z * Kslice;
  const int wr = (wave >> 1) * 64, wc = (wave & 1) * 64;
  Cf += (size_t)blockIdx.z * M * N;

  const short* ag = A + (size_t)(row0 + wave * 32 + (lane >> 2)) * K + (lane & 3) * 8;
  const short* bg = Bt + (size_t)(col0 + wave * 32 + (lane >> 2)) * K + (lane & 3) * 8;
  short* asl = &As[wave * 32 * 32];
  short* bsl = &Bs[wave * 32 * 32];

  f32x4 acc[4][4];
#pragma unroll
  for (int i = 0; i < 4; i++)
#pragma unroll
    for (int j = 0; j < 4; j++) acc[i][j] = (f32x4){0.f, 0.f, 0.f, 0.f};

  for (int k0 = kbase; k0 < kbase + Kslice; k0 += 32) {
    load_lds16(ag + k0, asl);
    load_lds16(ag + (size_t)16 * K + k0, asl + 16 * 32);
    load_lds16(bg + k0, bsl);
    load_lds16(bg + (size_t)16 * K + k0, bsl + 16 * 32);
    __syncthreads();

    short8 af[4], bfr[4];
#pragma unroll
    for (int i = 0; i < 4; i++)
      af[i] = *(const short8*)(&As[(wr + 16 * i + lm) * 32 + lq * 8]);
#pragma unroll
    for (int j = 0; j < 4; j++)
      bfr[j] = *(const short8*)(&Bs[(wc + 16 * j + lm) * 32 + lq * 8]);
#pragma unroll
    for (int i = 0; i < 4; i++)
#pragma unroll
      for (int j = 0; j < 4; j++) acc[i][j] = mfma16(af[i], bfr[j], acc[i][j]);
    __syncthreads();
  }

#pragma unroll
  for (int i = 0; i < 4; i++) {
#pragma unroll
    for (int j = 0; j < 4; j++) {
      const int col = col0 + wc + 16 * j + lm;
#pragma unroll
      for (int r = 0; r < 4; r++) {
        const int row = row0 + wr + 16 * i + lq * 4 + r;
        Cf[(size_t)row * N + col] = acc[i][j][r];
      }
    }
  }
}

// ---------------------------------------------------------------------------
// Fused attention, S^T form, non-online softmax, split-K x2.
// LDS exactly 32 KB: unpadded Ks/Vs [64][64] and per-wave Ps [32][64],
// XOR-swizzled in 16B units (phys = logical ^ (row&7)) -> conflict-free
// frag reads. Coalesced int4 staging, 2 barriers/iter. corr in bf16.
// Grid (NHEAD, S_LEN/128, BATCH*2); 4 waves x 32 queries.
// ---------------------------------------------------------------------------
__global__ __launch_bounds__(256, 4) void attn_kernel(
    const short* __restrict__ QKV,   // [NTOK][3072]: Q*0.125 | K | V
    const short* __restrict__ VT,    // [DMODEL][NTOK]
    const short* __restrict__ corrb, // [B][S][S] bf16
    float* __restrict__ Op,          // [2][NTOK][DMODEL] partial numerators
    float* __restrict__ lp) {        // [2][NTOK][NHEAD] partial denominators
  const int h = blockIdx.x, qtile = blockIdx.y;
  const int b = blockIdx.z >> 1, split = blockIdx.z & 1;
  const int koff = split * (S_LEN / 2);
  const int tid = threadIdx.x;
  const int wave = tid >> 6, lane = tid & 63;
  const int lm = lane & 15, lq = lane >> 4;
  const int qb = qtile * 128 + wave * 32;
  const int fx = lm & 7;  // read-side swizzle key

  __shared__ __attribute__((aligned(16))) short Ks[64 * 64];   // 8 KB
  __shared__ __attribute__((aligned(16))) short Vs[64 * 64];   // 8 KB
  __shared__ __attribute__((aligned(16))) short Ps[4 * 32 * 64];  // 16 KB

  const short* q0 = QKV + (size_t)(b * S_LEN + qb + lm) * QKVLD + h * DHEAD;
  const short* q1 = q0 + (size_t)16 * QKVLD;
  const short8 qA0 = *(const short8*)(q0 + lq * 8);
  const short8 qA1 = *(const short8*)(q0 + lq * 8 + 32);
  const short8 qB0 = *(const short8*)(q1 + lq * 8);
  const short8 qB1 = *(const short8*)(q1 + lq * 8 + 32);

  f32x4 oA[4], oB[4];
#pragma unroll
  for (int t = 0; t < 4; t++) {
    oA[t] = (f32x4){0.f, 0.f, 0.f, 0.f};
    oB[t] = (f32x4){0.f, 0.f, 0.f, 0.f};
  }
  f32x4 laccA = (f32x4){0.f, 0.f, 0.f, 0.f};
  f32x4 laccB = (f32x4){0.f, 0.f, 0.f, 0.f};

  const short* Kp = QKV + (size_t)(b * S_LEN) * QKVLD + DMODEL + h * DHEAD;
  const short* Vp = VT + (size_t)(h * DHEAD) * NTOK + b * S_LEN;
  const short* c0 = corrb + (size_t)(b * S_LEN + qb + lm) * S_LEN;
  const short* c1 = c0 + (size_t)16 * S_LEN;

  // staging: 4 threads per row; thread covers logical 16B-units su and su+4
  const int sr = tid >> 2;          // 0..63
  const int su = tid & 3;
  const int sw0 = (su ^ (sr & 7)) * 8;        // phys short-offset, unit su
  const int sw1 = ((su + 4) ^ (sr & 7)) * 8;  // unit su+4

  for (int kt = koff; kt < koff + S_LEN / 2; kt += 64) {
    const short* kr = Kp + (size_t)(kt + sr) * QKVLD + su * 8;
    const short* vr = Vp + (size_t)sr * NTOK + kt + su * 8;
    *(int4*)(&Ks[sr * 64 + sw0]) = *(const int4*)kr;
    *(int4*)(&Ks[sr * 64 + sw1]) = *(const int4*)(kr + 32);
    *(int4*)(&Vs[sr * 64 + sw0]) = *(const int4*)vr;
    *(int4*)(&Vs[sr * 64 + sw1]) = *(const int4*)(vr + 32);
    __syncthreads();

    // --- scores S^T for both q-groups (swizzled K frag reads)
    f32x4 svA[4], svB[4];
#pragma unroll
    for (int t = 0; t < 4; t++) {
      const int rb = (t * 16 + lm) * 64;
      const short8 kf0 = *(const short8*)(&Ks[rb + (lq ^ fx) * 8]);
      const short8 kf1 = *(const short8*)(&Ks[rb + ((lq + 4) ^ fx) * 8]);
      f32x4 a = (f32x4){0.f, 0.f, 0.f, 0.f};
      a = mfma16(kf0, qA0, a);
      a = mfma16(kf1, qA1, a);
      svA[t] = a;
      f32x4 c = (f32x4){0.f, 0.f, 0.f, 0.f};
      c = mfma16(kf0, qB0, c);
      c = mfma16(kf1, qB1, c);
      svB[t] = c;
    }

    // --- exp(s + corr), accumulate row sums, pack P (swizzled, wave-private)
#pragma unroll
    for (int t = 0; t < 4; t++) {
      const short4v crA = *(const short4v*)(c0 + kt + t * 16 + lq * 4);
      const short4v crB = *(const short4v*)(c1 + kt + t * 16 + lq * 4);
#pragma unroll
      for (int r = 0; r < 4; r++) {
        svA[t][r] = __expf(svA[t][r] + bs2f(crA[r]));
        svB[t][r] = __expf(svB[t][r] + bs2f(crB[r]));
      }
      laccA += svA[t];
      laccB += svB[t];
      short4v pA = {f2bs(svA[t][0]), f2bs(svA[t][1]), f2bs(svA[t][2]), f2bs(svA[t][3])};
      short4v pB = {f2bs(svB[t][0]), f2bs(svB[t][1]), f2bs(svB[t][2]), f2bs(svB[t][3])};
      const int pu = ((2 * t + (lq >> 1)) ^ fx) * 8 + (lq & 1) * 4;
      *(short4v*)(&Ps[wave * 2048 + lm * 64 + pu]) = pA;
      *(short4v*)(&Ps[wave * 2048 + (16 + lm) * 64 + pu]) = pB;
    }

    // --- PV (swizzled P and V frag reads)
    const int pbA = wave * 2048 + lm * 64;
    const int pbB = pbA + 16 * 64;
    const short8 pA0 = *(const short8*)(&Ps[pbA + (lq ^ fx) * 8]);
    const short8 pA1 = *(const short8*)(&Ps[pbA + ((lq + 4) ^ fx) * 8]);
    const short8 pB0 = *(const short8*)(&Ps[pbB + (lq ^ fx) * 8]);
    const short8 pB1 = *(const short8*)(&Ps[pbB + ((lq + 4) ^ fx) * 8]);
#pragma unroll
    for (int t = 0; t < 4; t++) {
      const int rb = (t * 16 + lm) * 64;
      const short8 vf0 = *(const short8*)(&Vs[rb + (lq ^ fx) * 8]);
      const short8 vf1 = *(const short8*)(&Vs[rb + ((lq + 4) ^ fx) * 8]);
      oA[t] = mfma16(vf0, pA0, oA[t]);
      oA[t] = mfma16(vf1, pA1, oA[t]);
      oB[t] = mfma16(vf0, pB0, oB[t]);
      oB[t] = mfma16(vf1, pB1, oB[t]);
    }
    __syncthreads();
  }

  // --- epilogue: partial sums out (no divide)
  float lA = laccA[0] + laccA[1] + laccA[2] + laccA[3];
  float lB = laccB[0] + laccB[1] + laccB[2] + laccB[3];
  lA += __shfl_xor(lA, 16);
  lA += __shfl_xor(lA, 32);
  lB += __shfl_xor(lB, 16);
  lB += __shfl_xor(lB, 32);
  if (lq == 0) {
    lp[((size_t)split * NTOK + b * S_LEN + qb + lm) * NHEAD + h] = lA;
    lp[((size_t)split * NTOK + b * S_LEN + qb + 16 + lm) * NHEAD + h] = lB;
  }
  float* opA = Op + (size_t)split * NTOK * DMODEL +
               (size_t)(b * S_LEN + qb + lm) * DMODEL + h * DHEAD;
  float* opB = opA + (size_t)16 * DMODEL;
#pragma unroll
  for (int t = 0; t < 4; t++) {
    *(f32x4*)(opA + t * 16 + lq * 4) = oA[t];
    *(f32x4*)(opB + t * 16 + lq * 4) = oB[t];
  }
}

// ---------------------------------------------------------------------------
// Combine split-K partials: ctx = (O0+O1)/(l0+l1), bf16
// ---------------------------------------------------------------------------
__global__ __launch_bounds__(256) void combine_ctx(
    const float* __restrict__ Op, const float* __restrict__ lp,
    short* __restrict__ ctx) {
  const size_t idx = ((size_t)blockIdx.x * 256 + threadIdx.x) * 4;
  const int token = (int)(idx >> 10);
  const int d = (int)(idx & 1023);
  const int h = d >> 6;
  const f32x4 o0 = *(const f32x4*)(Op + idx);
  const f32x4 o1 = *(const f32x4*)(Op + (size_t)NTOK * DMODEL + idx);
  const float l0 = lp[(size_t)token * NHEAD + h];
  const float l1 = lp[((size_t)NTOK + token) * NHEAD + h];
  const float inv = 1.0f / (l0 + l1);
  short4v ov = {f2bs((o0[0] + o1[0]) * inv), f2bs((o0[1] + o1[1]) * inv),
                f2bs((o0[2] + o1[2]) * inv), f2bs((o0[3] + o1[3]) * inv)};
  *(short4v*)(ctx + idx) = ov;
}

// ---------------------------------------------------------------------------
// Residual + 2 GEMM partials + bias + LayerNorm. One block per token row.
// v = xa + p0 + p1 + bias; out = LN(v)*g + be
// ---------------------------------------------------------------------------
__global__ __launch_bounds__(256) void residual_ln3(
    const float* __restrict__ xa, const float* __restrict__ p0,
    const float* __restrict__ p1, const float* __restrict__ bias,
    const float* __restrict__ g, const float* __restrict__ be,
    float* __restrict__ outf, short* __restrict__ outb) {
  const int row = blockIdx.x;
  const int t = threadIdx.x;
  const size_t base = (size_t)row * DMODEL + t * 4;
  float4 a = *(const float4*)(xa + base);
  f32x4 q0 = *(const f32x4*)(p0 + base);
  f32x4 q1 = *(const f32x4*)(p1 + base);
  f32x4 bb = *(const f32x4*)(bias + t * 4);
  const float v0 = a.x + q0[0] + q1[0] + bb[0];
  const float v1 = a.y + q0[1] + q1[1] + bb[1];
  const float v2 = a.z + q0[2] + q1[2] + bb[2];
  const float v3 = a.w + q0[3] + q1[3] + bb[3];
  float sum = v0 + v1 + v2 + v3;
  float sq = v0 * v0 + v1 * v1 + v2 * v2 + v3 * v3;
#pragma unroll
  for (int off = 1; off < 64; off <<= 1) {
    sum += __shfl_xor(sum, off);
    sq += __shfl_xor(sq, off);
  }
  __shared__ float ssum[4], ssq[4];
  const int wave = t >> 6;
  if ((t & 63) == 0) { ssum[wave] = sum; ssq[wave] = sq; }
  __syncthreads();
  sum = ssum[0] + ssum[1] + ssum[2] + ssum[3];
  sq = ssq[0] + ssq[1] + ssq[2] + ssq[3];
  const float mean = sum * (1.0f / DMODEL);
  const float var = sq * (1.0f / DMODEL) - mean * mean;
  const float rstd = rsqrtf(var + 1e-5f);
  float4 gv = *(const float4*)(g + t * 4);
  float4 bv = *(const float4*)(be + t * 4);
  const float o0 = (v0 - mean) * rstd * gv.x + bv.x;
  const float o1 = (v1 - mean) * rstd * gv.y + bv.y;
  const float o2 = (v2 - mean) * rstd * gv.z + bv.z;
  const float o3 = (v3 - mean) * rstd * gv.w + bv.w;
  if (outf) {
    float4 ov = {o0, o1, o2, o3};
    *(float4*)(outf + base) = ov;
  }
  if (outb) {
    short4v ob = {f2bs(o0), f2bs(o1), f2bs(o2), f2bs(o3)};
    *(short4v*)(outb + base) = ob;
  }
}

// ---------------------------------------------------------------------------
extern "C" void kernel_launch(void* const* d_in, const int* in_sizes, int n_in,
                              void* d_out, int out_size, void* d_ws, size_t ws_size,
                              hipStream_t stream) {
  const float* src = (const float*)d_in[0];
  const float* corr = (const float*)d_in[1];
  const float* pos = (const float*)d_in[2];
  const float* Wq = (const float*)d_in[3];
  const float* bq = (const float*)d_in[4];
  const float* Wk = (const float*)d_in[5];
  const float* bk = (const float*)d_in[6];
  const float* Wv = (const float*)d_in[7];
  const float* bv = (const float*)d_in[8];
  const float* Wo = (const float*)d_in[9];
  const float* bo = (const float*)d_in[10];
  const float* W1 = (const float*)d_in[11];
  const float* b1 = (const float*)d_in[12];
  const float* W2 = (const float*)d_in[13];
  const float* b2 = (const float*)d_in[14];
  const float* g1 = (const float*)d_in[15];
  const float* be1 = (const float*)d_in[16];
  const float* g2 = (const float*)d_in[17];
  const float* be2 = (const float*)d_in[18];
  float* out = (float*)d_out;

  char* ws = (char*)d_ws;
  size_t off = 0;
  auto alloc = [&](size_t bytes) {
    char* p = ws + off;
    off += (bytes + 255) & ~(size_t)255;
    return p;
  };
  short* WqkvT = (short*)alloc((size_t)QKVLD * DMODEL * 2);  // [3072][1024]
  short* WoT = (short*)alloc((size_t)DMODEL * DMODEL * 2);
  short* W1T = (short*)alloc((size_t)DFF * DMODEL * 2);
  short* W2T = (short*)alloc((size_t)DMODEL * DFF * 2);
  float* bqkv = (float*)alloc((size_t)QKVLD * 4);
  short* qkb = (short*)alloc((size_t)NTOK * DMODEL * 2);
  short* srcb = (short*)alloc((size_t)NTOK * DMODEL * 2);
  short* QKVb = (short*)alloc((size_t)NTOK * QKVLD * 2);   // fused Q|K|V (24 MB)
  short* VTt = (short*)alloc((size_t)DMODEL * NTOK * 2);
  short* corrb = (short*)alloc((size_t)BATCH * S_LEN * S_LEN * 2);  // 16.8 MB
  short* ctxb = (short*)alloc((size_t)NTOK * DMODEL * 2);
  float* lp = (float*)alloc((size_t)2 * NTOK * NHEAD * 4);
  float* Pp = (float*)alloc((size_t)2 * NTOK * DMODEL * 4);  // split-K partials (33.6 MB)
  float* x1f = (float*)alloc((size_t)NTOK * DMODEL * 4);
  short* x1b = (short*)alloc((size_t)NTOK * DMODEL * 2);
  short* Hb = (short*)alloc((size_t)NTOK * DFF * 2);       // 33.6 MB, aliases Op
  float* Op = (float*)Hb;                                  // [2][NTOK][DMODEL] f32

  const dim3 tb(32, 8);
  transpose_cast<<<dim3(32, 32), tb, 0, stream>>>(Wq, WqkvT, DMODEL, DMODEL, 0.125f);
  transpose_cast<<<dim3(32, 32), tb, 0, stream>>>(Wk, WqkvT + (size_t)DMODEL * DMODEL,
                                                  DMODEL, DMODEL, 1.0f);
  transpose_cast<<<dim3(32, 32), tb, 0, stream>>>(Wv, WqkvT + (size_t)2 * DMODEL * DMODEL,
                                                  DMODEL, DMODEL, 1.0f);
  transpose_cast<<<dim3(32, 32), tb, 0, stream>>>(Wo, WoT, DMODEL, DMODEL, 1.0f);
  transpose_cast<<<dim3(128, 32), tb, 0, stream>>>(W1, W1T, DMODEL, DFF, 1.0f);
  transpose_cast<<<dim3(32, 128), tb, 0, stream>>>(W2, W2T, DFF, DMODEL, 1.0f);
  concat_bias<<<QKVLD / 256, 256, 0, stream>>>(bq, bk, bv, bqkv);

  prep_tokens<<<(NTOK * DMODEL) / (256 * 4), 256, 0, stream>>>(src, pos, qkb, srcb);
  prep_corr<<<(BATCH * S_LEN * S_LEN) / (256 * 4), 256, 0, stream>>>(corr, corrb);

  // fused Q|K|V projection: cols<2048 use qkb, cols>=2048 use srcb
  gemm_bt<0, 1><<<dim3(QKVLD / 128, NTOK / 128), 256, 0, stream>>>(
      qkb, srcb, WqkvT, bqkv, nullptr, QKVb, NTOK, QKVLD, DMODEL, 2048);

  // V^T for attention PV a-operand (V = cols 2048.. of QKVb)
  transpose_bf16<<<dim3(DMODEL / 64, NTOK / 64), 256, 0, stream>>>(
      QKVb + 2048, VTt, NTOK, QKVLD);

  // attention, split-K x2 (1024 blocks, 32 KB LDS -> 4 blocks/CU)
  attn_kernel<<<dim3(NHEAD, S_LEN / 128, BATCH * 2), 256, 0, stream>>>(
      QKVb, VTt, corrb, Op, lp);
  combine_ctx<<<(NTOK * DMODEL) / (256 * 4), 256, 0, stream>>>(Op, lp, ctxb);

  // output projection: split-K x2 partials, summed in LN1
  gemm_bt_part<<<dim3(DMODEL / 128, NTOK / 128, 2), 256, 0, stream>>>(
      ctxb, WoT, Pp, NTOK, DMODEL, DMODEL, DMODEL / 2);

  // LN1: x1 = LN(src + P0 + P1 + bo)
  residual_ln3<<<NTOK, 256, 0, stream>>>(src, Pp, Pp + (size_t)NTOK * DMODEL,
                                         bo, g1, be1, x1f, x1b);

  // FFN1 (128x128, 1024 blocks)
  gemm_bt<1, 1><<<dim3(DFF / 128, NTOK / 128), 256, 0, stream>>>(
      x1b, x1b, W1T, b1, nullptr, Hb, NTOK, DFF, DMODEL, 1 << 30);

  // FFN2: split-K x2 partials, summed in LN2
  gemm_bt_part<<<dim3(DMODEL / 128, NTOK / 128, 2), 256, 0, stream>>>(
      Hb, W2T, Pp, NTOK, DMODEL, DFF, DFF / 2);

  // LN2 -> output
  residual_ln3<<<NTOK, 256, 0, stream>>>(x1f, Pp, Pp + (size_t)NTOK * DMODEL,
                                         b2, g2, be2, out, nullptr);
}